// Round 11
// baseline (260.857 us; speedup 1.0000x reference)
//
#include <hip/hip_runtime.h>

// ConvLSTM2D MI355X, R11: R10 (persistent, targeted coherence) with the
// barrier poll/arrive moved from inline-asm to __hip_atomic_* intrinsics.
// R10's failure was a compiler-scheduling bug (compare on the asm load's
// output hoisted above the s_waitcnt -> early barrier exit -> stale h), the
// rule-#18 hazard class. Intrinsics give the compiler the data dependency.
// Design: only h crosses XCDs -> h stores/loads use sc0 sc1 (system scope);
// no agent fences; L2 stays warm for weights/x across all 10 steps; c in
// registers. Geometry = R9: 256 blocks [b8][tile16][fh2] x 512 thr.

typedef __attribute__((ext_vector_type(8))) short short8v;
typedef __attribute__((ext_vector_type(4))) float f32x4;
typedef unsigned short u16;

__device__ __forceinline__ u16 f2bf(float x) {
    union { float f; unsigned u; } a; a.f = x;
    unsigned r = a.u + 0x7FFFu + ((a.u >> 16) & 1u);   // RNE
    return (u16)(r >> 16);
}
__device__ __forceinline__ float sigf(float x) { return 1.0f / (1.0f + __expf(-x)); }
__device__ __forceinline__ float tanhf_(float x) {
    float e = __expf(2.0f * x);
    return 1.0f - 2.0f / (e + 1.0f);
}

// ---- prep: x f32 -> bf16 ----
__global__ __launch_bounds__(256)
void prep_x(const float* __restrict__ x, u16* __restrict__ xb) {
    size_t i = (size_t)blockIdx.x * 256 + threadIdx.x;
    for (; i < 2621440u; i += (size_t)2048 * 256) {
        float4 v = ((const float4*)x)[i];
        union { u16 u[4]; uint2 q; } o;
        o.u[0] = f2bf(v.x); o.u[1] = f2bf(v.y);
        o.u[2] = f2bf(v.z); o.u[3] = f2bf(v.w);
        ((uint2*)xb)[i] = o.q;
    }
}

// ---- prep: weights -> staged layout + zero barrier counters ----
// wt_in[tap9][kb4][fh2][n4][fi32][8i], wt_rk[g4][cc18][kb4][fh2][n4][fi32][8i]
__global__ __launch_bounds__(256)
void prep_w(const float* __restrict__ kern, const float* __restrict__ rk,
            u16* __restrict__ wt_in, u16* __restrict__ wt_rk,
            unsigned* __restrict__ cnt) {
    int idx = blockIdx.x * 256 + threadIdx.x;
    if (blockIdx.x == 0 && threadIdx.x < 16) cnt[threadIdx.x] = 0u;
    if (idx >= 82944) return;
    const float* s;
    u16* dst;
    if (idx < 9216) {
        int fi = idx & 31, r1 = idx >> 5;
        int n = r1 & 3, r2 = r1 >> 2;
        int fh = r2 & 1, r3 = r2 >> 1;
        int kb = r3 & 3, tap = r3 >> 2;
        int co = (n << 6) + (fh << 5) + fi;
        s = kern + (size_t)((tap << 5) + (kb << 3)) * 256 + co;
        dst = wt_in + (size_t)idx * 8;
    } else {
        int j = idx - 9216;
        int fi = j & 31, r1 = j >> 5;
        int n = r1 & 3, r2 = r1 >> 2;
        int fh = r2 & 1, r3 = r2 >> 1;
        int kb = r3 & 3, r4 = r3 >> 2;           // 0..71 = g*18+cc
        int g = r4 / 18, cc = r4 - g * 18;
        int tap = cc >> 1;
        int cib = (cc & 1) << 5;
        int co = (n << 6) + (fh << 5) + fi;
        s = rk + (size_t)(((g * 9 + tap) << 6) + cib + (kb << 3)) * 256 + co;
        dst = wt_rk + (size_t)j * 8;
    }
    union { u16 u[8]; uint4 q; } o;
    #pragma unroll
    for (int i = 0; i < 8; ++i) o.u[i] = f2bf(s[i * 256]);
    *(uint4*)dst = o.q;
}

// ---- persistent fused conv + gates, all timesteps ----
__global__ __launch_bounds__(512)
void lstm_all(const u16* __restrict__ xb, const u16* __restrict__ wt_in,
              const u16* __restrict__ wt_rk, const float* __restrict__ bias,
              const int* __restrict__ labels,
              u16* __restrict__ hb0, u16* __restrict__ hb1,
              float* __restrict__ out, unsigned* __restrict__ cnt)
{
    // X halo @0: [kb4][324][8] (10368 shorts); H halo @10368: [kb8][324][8]
    __shared__ short hal[31104];   // 62,208 B

    const int tid  = threadIdx.x;
    const int lane = tid & 63;
    const int w    = tid >> 6;
    const int pxq  = w >> 1;
    const int wq   = w & 1;
    const int bid  = blockIdx.x;
    const int fh   = bid & 1;
    const int tile = (bid >> 1) & 15;
    const int b    = bid >> 5;
    const int y0 = (tile >> 2) << 4, x0 = (tile & 3) << 4;
    const int g = labels[b];

    const int co_l = lane & 15;
    const int kbl  = lane >> 4;
    const int prow = (lane & 15) >> 3, pcol = lane & 7;
    const int fi = (wq << 4) + co_l;
    const int f  = (fh << 5) + fi;

    float bv[4];
    #pragma unroll
    for (int n = 0; n < 4; ++n)
        bv[n] = bias[(g << 8) + (n << 6) + f];

    int aoffm[4];
    #pragma unroll
    for (int mf = 0; mf < 4; ++mf)
        aoffm[mf] = ((pxq << 2) + ((mf >> 1) << 1) + prow) * 18 + ((mf & 1) << 3) + pcol;

    // output offsets (16 px per thread) within one [4096][64] image
    int coff[4][4];
    #pragma unroll
    for (int mf = 0; mf < 4; ++mf)
        #pragma unroll
        for (int rr = 0; rr < 4; ++rr) {
            int pf = (kbl << 2) + rr;
            int yy = y0 + (pxq << 2) + ((mf >> 1) << 1) + (pf >> 3);
            int xx = x0 + ((mf & 1) << 3) + (pf & 7);
            coff[mf][rr] = (((yy << 6) + xx) << 6) + f;
        }

    // c state in registers for the whole sequence
    float cst[4][4];
    #pragma unroll
    for (int mf = 0; mf < 4; ++mf)
        #pragma unroll
        for (int rr = 0; rr < 4; ++rr) cst[mf][rr] = 0.0f;

    const u16* xsrc0 = xb + ((size_t)b * 10 << 17);
    float*     ob0   = out + ((size_t)b * 10 << 18);
    unsigned*  cbase = cnt;

    // ---- stage X(0) halo ----
    {
        const u16* src = xsrc0;
        #pragma unroll 2
        for (int s = tid; s < 1296; s += 512) {
            int pos = s >> 2, kb = s & 3;
            int hy = pos / 18, hx = pos - hy * 18;
            int gy = y0 + hy - 1, gx = x0 + hx - 1;
            short8v v = (short8v){0,0,0,0,0,0,0,0};
            if ((unsigned)gy < 64u && (unsigned)gx < 64u)
                v = *(const short8v*)&src[(((gy << 6) + gx) << 5) + (kb << 3)];
            *(short8v*)&hal[kb * 2592 + pos * 8] = v;
        }
    }
    __syncthreads();

    for (int t = 0; t < 10; ++t) {
        u16* hwr = ((t & 1) ? hb1 : hb0) + ((size_t)b << 18);

        f32x4 acc[4][4];
        #pragma unroll
        for (int n = 0; n < 4; ++n)
            #pragma unroll
            for (int mf = 0; mf < 4; ++mf)
                acc[mf][n] = (f32x4){bv[n], bv[n], bv[n], bv[n]};

        // ---- phase X: 9 chunks ----
        #pragma unroll 3
        for (int tap = 0; tap < 9; ++tap) {
            const int koff = (tap / 3) * 18 + (tap % 3);
            const u16* wb = wt_in + (size_t)((((tap << 2) + kbl) << 1) + fh) * 1024 + fi * 8;
            short8v bfr[4], af[4];
            #pragma unroll
            for (int n = 0; n < 4; ++n)
                bfr[n] = *(const short8v*)&wb[n * 256];
            #pragma unroll
            for (int mf = 0; mf < 4; ++mf)
                af[mf] = *(const short8v*)&hal[kbl * 2592 + (aoffm[mf] + koff) * 8];
            #pragma unroll
            for (int mf = 0; mf < 4; ++mf)
                #pragma unroll
                for (int n = 0; n < 4; ++n)
                    acc[mf][n] = __builtin_amdgcn_mfma_f32_16x16x32_bf16(af[mf], bfr[n], acc[mf][n], 0, 0, 0);
        }

        // ---- phase H: 18 chunks ----
        if (t > 0) {
            #pragma unroll 3
            for (int c = 0; c < 18; ++c) {
                const int tap = c >> 1;
                const int koff = (tap / 3) * 18 + (tap % 3);
                const u16* wb = wt_rk + (size_t)(((((g * 18 + c) << 2) + kbl) << 1) + fh) * 1024 + fi * 8;
                short8v bfr[4], af[4];
                #pragma unroll
                for (int n = 0; n < 4; ++n)
                    bfr[n] = *(const short8v*)&wb[n * 256];
                const int abase = 10368 + (((c & 1) << 2) + kbl) * 2592;
                #pragma unroll
                for (int mf = 0; mf < 4; ++mf)
                    af[mf] = *(const short8v*)&hal[abase + (aoffm[mf] + koff) * 8];
                #pragma unroll
                for (int mf = 0; mf < 4; ++mf)
                    #pragma unroll
                    for (int n = 0; n < 4; ++n)
                        acc[mf][n] = __builtin_amdgcn_mfma_f32_16x16x32_bf16(af[mf], bfr[n], acc[mf][n], 0, 0, 0);
            }
        }

        // ---- gates in-register + writeback ----
        float* ob = ob0 + ((size_t)t << 18);
        #pragma unroll
        for (int mf = 0; mf < 4; ++mf) {
            #pragma unroll
            for (int rr = 0; rr < 4; ++rr) {
                int off = coff[mf][rr];
                float zi = acc[mf][0][rr], zf = acc[mf][1][rr];
                float zg = acc[mf][2][rr], zo = acc[mf][3][rr];
                float cn = sigf(zf) * cst[mf][rr] + sigf(zi) * tanhf_(zg);
                float hn = sigf(zo) * tanhf_(cn);
                cst[mf][rr] = cn;
                ob[off] = hn;                          // normal cached store
                unsigned hb16 = (unsigned)f2bf(hn);    // h: system-scope store
                const u16* hp = hwr + off;
                asm volatile("global_store_short %0, %1, off sc0 sc1"
                             :: "v"(hp), "v"(hb16) : "memory");
            }
        }

        if (t < 9) {
            // ---- grid barrier: arrive (intrinsics, compiler-ordered) ----
            asm volatile("s_waitcnt vmcnt(0)" ::: "memory");  // h stores visible
            __syncthreads();
            if (tid == 0) {
                __hip_atomic_fetch_add(cbase + t, 1u, __ATOMIC_RELAXED,
                                       __HIP_MEMORY_SCOPE_SYSTEM);
            }
            // stage X(t+1) while other blocks arrive (h-independent)
            {
                const u16* src = xsrc0 + ((size_t)(t + 1) << 17);
                #pragma unroll 2
                for (int s = tid; s < 1296; s += 512) {
                    int pos = s >> 2, kb = s & 3;
                    int hy = pos / 18, hx = pos - hy * 18;
                    int gy = y0 + hy - 1, gx = x0 + hx - 1;
                    short8v v = (short8v){0,0,0,0,0,0,0,0};
                    if ((unsigned)gy < 64u && (unsigned)gx < 64u)
                        v = *(const short8v*)&src[(((gy << 6) + gx) << 5) + (kb << 3)];
                    *(short8v*)&hal[kb * 2592 + pos * 8] = v;
                }
            }
            // ---- poll (intrinsic load: compiler inserts waitcnt before use) ----
            if (tid == 0) {
                int guard = 0;
                while (__hip_atomic_load(cbase + t, __ATOMIC_RELAXED,
                                         __HIP_MEMORY_SCOPE_SYSTEM) < 256u
                       && guard < (1 << 18)) {
                    __builtin_amdgcn_s_sleep(1);
                    ++guard;
                }
            }
            __syncthreads();   // all blocks' h(t) globally visible

            // ---- stage H(t+1) halo via system-scope loads (bypass stale L2) ----
            {
                const u16* hsrc = ((t & 1) ? hb1 : hb0) + ((size_t)b << 18);
                uint4 hv[6];
                int   ls[6];
                bool  okv[6], inbv[6];
                #pragma unroll
                for (int u = 0; u < 6; ++u) {
                    int s = tid + (u << 9);
                    okv[u] = s < 2592;
                    int pos = s >> 3, kb = s & 7;
                    int hy = pos / 18, hx = pos - hy * 18;
                    int gy = y0 + hy - 1, gx = x0 + hx - 1;
                    inbv[u] = okv[u] && (unsigned)gy < 64u && (unsigned)gx < 64u;
                    const u16* ga = inbv[u] ? &hsrc[(((gy << 6) + gx) << 6) + (kb << 3)]
                                            : hsrc;
                    asm volatile("global_load_dwordx4 %0, %1, off sc0 sc1"
                                 : "=v"(hv[u]) : "v"(ga) : "memory");
                    ls[u] = 10368 + kb * 2592 + pos * 8;
                }
                asm volatile("s_waitcnt vmcnt(0)" ::: "memory");
                __builtin_amdgcn_sched_barrier(0);
                #pragma unroll
                for (int u = 0; u < 6; ++u) {
                    if (okv[u]) {
                        uint4 v = hv[u];
                        if (!inbv[u]) { v.x = 0; v.y = 0; v.z = 0; v.w = 0; }
                        *(uint4*)&hal[ls[u]] = v;
                    }
                }
            }
            __syncthreads();   // halos ready for step t+1
        }
    }
}

extern "C" void kernel_launch(void* const* d_in, const int* in_sizes, int n_in,
                              void* d_out, int out_size, void* d_ws, size_t ws_size,
                              hipStream_t stream)
{
    const float* x    = (const float*)d_in[0];
    const int*   lbl  = (const int*)  d_in[1];
    const float* kern = (const float*)d_in[2];
    const float* rk   = (const float*)d_in[3];
    const float* bias = (const float*)d_in[4];
    float* out = (float*)d_out;

    // ws: xb 20.97MB | hb0 4.19 | hb1 4.19 | wt_in 0.147 | wt_rk 1.18 | cnt
    u16* xb    = (u16*)d_ws;
    u16* hb0   = xb + 10485760;
    u16* hb1   = hb0 + 2097152;
    u16* wt_in = hb1 + 2097152;
    u16* wt_rk = wt_in + 73728;
    unsigned* cnt = (unsigned*)(wt_rk + 589824);

    hipLaunchKernelGGL(prep_x, dim3(2048), dim3(256), 0, stream, x, xb);
    hipLaunchKernelGGL(prep_w, dim3(324), dim3(256), 0, stream,
                       kern, rk, wt_in, wt_rk, cnt);

    void* args[] = { (void*)&xb, (void*)&wt_in, (void*)&wt_rk, (void*)&bias,
                     (void*)&lbl, (void*)&hb0, (void*)&hb1, (void*)&out,
                     (void*)&cnt };
    hipLaunchCooperativeKernel((const void*)lstm_all, dim3(256), dim3(512),
                               args, 0, stream);
}

// Round 13
// 209.255 us; speedup vs baseline: 1.2466x; 1.2466x over previous
//
#include <hip/hip_runtime.h>

// ConvLSTM2D MI355X, R13: R12 (persistent + LOCAL 8-neighbor sync) with the
// inline-asm 128-bit operands moved to ext_vector_type(4) (clang rejects HIP
// struct uint4 as asm INPUT: "indirect register inputs").
// Block = (b, 16x8 tile) x all 256 co. h interior -> next step's H-halo LDS
// directly (never global); only 44-px tile boundary exported (sc0sc1 16B) and
// 52-px halo ring imported. Per-tile flags; poll 8 neighbors only (wave0,
// __all). Weights/X stay L2-warm; c in registers; X staged inline from f32.

typedef __attribute__((ext_vector_type(8))) short short8v;
typedef __attribute__((ext_vector_type(4))) float f32x4;
typedef __attribute__((ext_vector_type(4))) unsigned int u32x4;
typedef unsigned short u16;

__device__ __forceinline__ u16 f2bf(float x) {
    union { float f; unsigned u; } a; a.f = x;
    unsigned r = a.u + 0x7FFFu + ((a.u >> 16) & 1u);   // RNE
    return (u16)(r >> 16);
}
__device__ __forceinline__ float sigf(float x) { return 1.0f / (1.0f + __expf(-x)); }
__device__ __forceinline__ float tanhf_(float x) {
    float e = __expf(2.0f * x);
    return 1.0f - 2.0f / (e + 1.0f);
}

// ---- prep: weights -> staged layout + zero flags ----
__global__ __launch_bounds__(256)
void prep_w(const float* __restrict__ kern, const float* __restrict__ rk,
            u16* __restrict__ wt_in, u16* __restrict__ wt_rk,
            unsigned* __restrict__ flags) {
    int idx = blockIdx.x * 256 + threadIdx.x;
    if (blockIdx.x == 0) flags[threadIdx.x] = 0u;
    if (idx >= 82944) return;
    const float* s;
    u16* dst;
    if (idx < 9216) {
        int co = idx & 255, ckb = idx >> 8;          // 0..35 = tap*4+kb
        int tap = ckb >> 2, kb = ckb & 3;
        s = kern + (size_t)((tap << 5) + (kb << 3)) * 256 + co;
        dst = wt_in + (size_t)idx * 8;
    } else {
        int j = idx - 9216;
        int co = j & 255, rest = j >> 8;             // 0..287
        int kb = rest & 3, gc = rest >> 2;           // gc = g*18 + cc
        int g = gc / 18, cc = gc - g * 18;
        int tap = cc >> 1;
        int cib = (cc & 1) << 5;
        s = rk + (size_t)(((g * 9 + tap) << 6) + cib + (kb << 3)) * 256 + co;
        dst = wt_rk + (size_t)j * 8;
    }
    union { u16 u[8]; uint4 q; } o;
    #pragma unroll
    for (int i = 0; i < 8; ++i) o.u[i] = f2bf(s[i * 256]);
    *(uint4*)dst = o.q;
}

__device__ __forceinline__ void stageX(const float* __restrict__ src,
                                       short* __restrict__ halX,
                                       int tid, int y0, int x0) {
    #pragma unroll 2
    for (int s = tid; s < 720; s += 512) {
        int pos = s >> 2, kb = s & 3;
        int hy = pos / 10, hx = pos - hy * 10;
        int gy = y0 + hy - 1, gx = x0 + hx - 1;
        union { u16 u[8]; short8v v; } o;
        o.v = (short8v){0,0,0,0,0,0,0,0};
        if ((unsigned)gy < 64u && (unsigned)gx < 64u) {
            const float* p = src + (((gy << 6) + gx) << 5) + (kb << 3);
            float4 a0 = *(const float4*)p;
            float4 a1 = *(const float4*)(p + 4);
            o.u[0] = f2bf(a0.x); o.u[1] = f2bf(a0.y);
            o.u[2] = f2bf(a0.z); o.u[3] = f2bf(a0.w);
            o.u[4] = f2bf(a1.x); o.u[5] = f2bf(a1.y);
            o.u[6] = f2bf(a1.z); o.u[7] = f2bf(a1.w);
        }
        *(short8v*)&halX[kb * 1440 + pos * 8] = o.v;
    }
}

// ---- persistent fused conv + gates, all timesteps ----
__global__ __launch_bounds__(512)
void lstm_all(const float* __restrict__ xf,   // (8,10,64,64,32) f32
              const u16* __restrict__ wt_in, const u16* __restrict__ wt_rk,
              const float* __restrict__ bias, const int* __restrict__ labels,
              u16* __restrict__ hb0, u16* __restrict__ hb1,  // h ring bufs
              float* __restrict__ out, unsigned* __restrict__ flags)
{
    // X halo @0: [kb4][180][8] (5760 shorts); H halo @5760: [kb8][180][8]
    __shared__ short hal[17280];   // 34,560 B

    const int tid  = threadIdx.x;
    const int lane = tid & 63;
    const int w    = tid >> 6;
    const int pxh  = w >> 2;                   // pixel half (rows 0-7 / 8-15)
    const int wq   = w & 3;                    // f-slice of 16
    const int b    = blockIdx.x >> 5;
    const int tile = blockIdx.x & 31;
    const int ty = tile >> 3, tx = tile & 7;
    const int y0 = ty << 4, x0 = tx << 3;
    const int g = labels[b];

    const int co_l = lane & 15;
    const int kbl  = lane >> 4;
    const int prow = (lane & 15) >> 3, pcol = lane & 7;
    const int f = (wq << 4) + co_l;

    float bv[4];
    #pragma unroll
    for (int n = 0; n < 4; ++n)
        bv[n] = bias[(g << 8) + (n << 6) + f];

    int aoffm[4];
    #pragma unroll
    for (int m = 0; m < 4; ++m)
        aoffm[m] = ((pxh << 3) + (m << 1) + prow) * 10 + pcol;

    int poff[4][4];
    #pragma unroll
    for (int m = 0; m < 4; ++m)
        #pragma unroll
        for (int rr = 0; rr < 4; ++rr) {
            int pf = (kbl << 2) + rr;
            int yy = y0 + (pxh << 3) + (m << 1) + (pf >> 3);
            int xx = x0 + (pf & 7);
            poff[m][rr] = (((yy << 6) + xx) << 6) + f;
        }

    float cst[4][4];
    #pragma unroll
    for (int m = 0; m < 4; ++m)
        #pragma unroll
        for (int rr = 0; rr < 4; ++rr) cst[m][rr] = 0.0f;

    const float* xsrc = xf + ((size_t)b * 10 << 17);
    float*       ob0  = out + ((size_t)b * 10 << 18);
    unsigned*    myfl = flags + (b << 5) + tile;

    // zero H halo region (out-of-image ring cells must stay 0 forever)
    for (int s = tid; s < 1440; s += 512)
        *(short8v*)&hal[5760 + s * 8] = (short8v){0,0,0,0,0,0,0,0};
    // stage X(0)
    stageX(xsrc, hal, tid, y0, x0);
    __syncthreads();

    for (int t = 0; t < 10; ++t) {
        u16* hw = ((t & 1) ? hb1 : hb0) + ((size_t)b << 18);

        f32x4 acc[4][4];
        #pragma unroll
        for (int n = 0; n < 4; ++n)
            #pragma unroll
            for (int m = 0; m < 4; ++m)
                acc[m][n] = (f32x4){bv[n], bv[n], bv[n], bv[n]};

        // ---- phase X: 9 chunks ----
        #pragma unroll 3
        for (int tap = 0; tap < 9; ++tap) {
            const int koff = (tap / 3) * 10 + (tap % 3);
            const u16* wb = wt_in + (size_t)((((tap << 2) + kbl) << 8) + (wq << 4) + co_l) * 8;
            short8v bfr[4], af[4];
            #pragma unroll
            for (int n = 0; n < 4; ++n)
                bfr[n] = *(const short8v*)&wb[(size_t)n << 9];
            #pragma unroll
            for (int m = 0; m < 4; ++m)
                af[m] = *(const short8v*)&hal[kbl * 1440 + (aoffm[m] + koff) * 8];
            #pragma unroll
            for (int m = 0; m < 4; ++m)
                #pragma unroll
                for (int n = 0; n < 4; ++n)
                    acc[m][n] = __builtin_amdgcn_mfma_f32_16x16x32_bf16(af[m], bfr[n], acc[m][n], 0, 0, 0);
        }
        // ---- phase H: 18 chunks ----
        if (t > 0) {
            #pragma unroll 3
            for (int c = 0; c < 18; ++c) {
                const int tap = c >> 1;
                const int koff = (tap / 3) * 10 + (tap % 3);
                const u16* wb = wt_rk + (size_t)(((((g * 18 + c) << 2) + kbl) << 8) + (wq << 4) + co_l) * 8;
                short8v bfr[4], af[4];
                #pragma unroll
                for (int n = 0; n < 4; ++n)
                    bfr[n] = *(const short8v*)&wb[(size_t)n << 9];
                const int abase = 5760 + (((c & 1) << 2) + kbl) * 1440;
                #pragma unroll
                for (int m = 0; m < 4; ++m)
                    af[m] = *(const short8v*)&hal[abase + (aoffm[m] + koff) * 8];
                #pragma unroll
                for (int m = 0; m < 4; ++m)
                    #pragma unroll
                    for (int n = 0; n < 4; ++n)
                        acc[m][n] = __builtin_amdgcn_mfma_f32_16x16x32_bf16(af[m], bfr[n], acc[m][n], 0, 0, 0);
            }
        }
        __syncthreads();   // sync1: all waves done reading H-LDS (h(t-1))

        // ---- gates + out store + h(t) interior direct to LDS ----
        float* ob = ob0 + ((size_t)t << 18);
        #pragma unroll
        for (int m = 0; m < 4; ++m) {
            #pragma unroll
            for (int rr = 0; rr < 4; ++rr) {
                float zi = acc[m][0][rr], zf = acc[m][1][rr];
                float zg = acc[m][2][rr], zo = acc[m][3][rr];
                float cn = sigf(zf) * cst[m][rr] + sigf(zi) * tanhf_(zg);
                float hn = sigf(zo) * tanhf_(cn);
                cst[m][rr] = cn;
                ob[poff[m][rr]] = hn;
                int pf = (kbl << 2) + rr;
                int ly = (pxh << 3) + (m << 1) + (pf >> 3);
                int lx = pf & 7;
                hal[5760 + (f >> 3) * 1440 + ((ly + 1) * 10 + lx + 1) * 8 + (f & 7)]
                    = (short)f2bf(hn);
            }
        }
        __syncthreads();   // sync2: LDS h(t) complete

        if (t < 9) {
            // ---- ring export: 44 boundary px x 8 ch-units, sc0sc1 16B ----
            if (tid < 352) {
                int pxr = tid >> 3, kb = tid & 7;
                int dy, dx;
                if (pxr < 8)       { dy = 0;  dx = pxr; }
                else if (pxr < 16) { dy = 15; dx = pxr - 8; }
                else { int v = pxr - 16; dy = 1 + (v >> 1); dx = (v & 1) * 7; }
                u32x4 v = *(const u32x4*)&hal[5760 + kb * 1440 + ((dy + 1) * 10 + dx + 1) * 8];
                const u16* ga = hw + ((((y0 + dy) << 6) + x0 + dx) << 6) + (kb << 3);
                asm volatile("global_store_dwordx4 %0, %1, off sc0 sc1"
                             :: "v"(ga), "v"(v) : "memory");
            }
            asm volatile("s_waitcnt vmcnt(0)" ::: "memory");
            __syncthreads();   // sync3: all ring stores drained
            if (tid == 0)
                __hip_atomic_fetch_add(myfl, 1u, __ATOMIC_RELAXED,
                                       __HIP_MEMORY_SCOPE_SYSTEM);

            // ---- stage X(t+1) while neighbors arrive ----
            stageX(xsrc + ((size_t)(t + 1) << 17), hal, tid, y0, x0);

            // ---- poll 8 neighbor flags (wave 0) ----
            if (tid < 64) {
                int k = tid;
                bool valid = false; int fidx = 0;
                if (k < 8) {
                    int kk = k + (k >= 4);           // 0..8 skipping center 4
                    int nty = ty + kk / 3 - 1, ntx = tx + kk % 3 - 1;
                    valid = (unsigned)nty < 4u && (unsigned)ntx < 8u;
                    fidx = (b << 5) + (nty << 3) + ntx;
                }
                unsigned tgt = (unsigned)(t + 1);
                int guard = 0;
                for (;;) {
                    unsigned vv = tgt;
                    if (valid)
                        vv = __hip_atomic_load(flags + fidx, __ATOMIC_RELAXED,
                                               __HIP_MEMORY_SCOPE_SYSTEM);
                    if (__all(vv >= tgt)) break;
                    if (++guard > (1 << 18)) break;
                    __builtin_amdgcn_s_sleep(2);
                }
            }
            __syncthreads();   // sync4: neighbors' h(t) rings visible

            // ---- ring import: 52 halo-ring px x 8 units, sc0sc1 16B ----
            if (tid < 416) {
                int posr = tid >> 3, kb = tid & 7;
                int hy, hx;
                if (posr < 10)      { hy = 0;  hx = posr; }
                else if (posr < 20) { hy = 17; hx = posr - 10; }
                else { int v = posr - 20; hy = 1 + (v >> 1); hx = (v & 1) * 9; }
                int gy = y0 + hy - 1, gx = x0 + hx - 1;
                bool inb = (unsigned)gy < 64u && (unsigned)gx < 64u;
                const u16* ga = inb ? (hw + (((gy << 6) + gx) << 6) + (kb << 3)) : hw;
                u32x4 v;
                asm volatile("global_load_dwordx4 %0, %1, off sc0 sc1"
                             : "=v"(v) : "v"(ga) : "memory");
                asm volatile("s_waitcnt vmcnt(0)" ::: "memory");
                __builtin_amdgcn_sched_barrier(0);
                if (!inb) v = (u32x4){0u, 0u, 0u, 0u};
                *(u32x4*)&hal[5760 + kb * 1440 + (hy * 10 + hx) * 8] = v;
            }
            __syncthreads();   // sync5: halos ready for step t+1
        }
    }
}

extern "C" void kernel_launch(void* const* d_in, const int* in_sizes, int n_in,
                              void* d_out, int out_size, void* d_ws, size_t ws_size,
                              hipStream_t stream)
{
    const float* x    = (const float*)d_in[0];
    const int*   lbl  = (const int*)  d_in[1];
    const float* kern = (const float*)d_in[2];
    const float* rk   = (const float*)d_in[3];
    const float* bias = (const float*)d_in[4];
    float* out = (float*)d_out;

    // ws: hb0 4.19MB | hb1 4.19MB | wt_in 0.147 | wt_rk 1.18 | flags 1KB
    u16* hb0   = (u16*)d_ws;
    u16* hb1   = hb0 + 2097152;
    u16* wt_in = hb1 + 2097152;
    u16* wt_rk = wt_in + 73728;
    unsigned* flags = (unsigned*)(wt_rk + 589824);

    hipLaunchKernelGGL(prep_w, dim3(324), dim3(256), 0, stream,
                       kern, rk, wt_in, wt_rk, flags);

    void* args[] = { (void*)&x, (void*)&wt_in, (void*)&wt_rk, (void*)&bias,
                     (void*)&lbl, (void*)&hb0, (void*)&hb1, (void*)&out,
                     (void*)&flags };
    (void)hipLaunchCooperativeKernel((const void*)lstm_all, dim3(256), dim3(512),
                                     args, 0, stream);
}